// Round 1
// baseline (545.157 us; speedup 1.0000x reference)
//
#include <hip/hip_runtime.h>

// FusedModConv: B=4, Cin=64, H=W=512, Cout=64, K=3, wdim=512.
// Strategy: prep kernel computes modulated+demodulated weights in fp32 and
// stores bf16 in MFMA-A-fragment-swizzled layout; conv kernel is an implicit
// GEMM (C[co][pix]) using mfma_f32_16x16x32_bf16, x staged to LDS as bf16
// [row][col][ci(pad 72)], weights read per-fragment from L2.

typedef __bf16 bf16x8 __attribute__((ext_vector_type(8)));
typedef float f32x4 __attribute__((ext_vector_type(4)));
typedef unsigned short ushortx8 __attribute__((ext_vector_type(8)));

#define CIN   64
#define COUT  64
#define HH    512
#define WW    512
#define WDIM  512

// tile: 8 rows x 32 cols of output pixels, all 64 co
#define TILE_H 8
#define TILE_W 32
#define XR     10   // TILE_H + 2
#define XC     34   // TILE_W + 2
#define CPAD   72   // 64 ci padded to 72 (bank-balanced b128 LDS reads)

__device__ __forceinline__ unsigned short f2bf(float f) {
    unsigned int u = __float_as_uint(f);
    unsigned int r = (u + 0x7FFFu + ((u >> 16) & 1u)) >> 16;  // RNE
    return (unsigned short)r;
}

// ---------------------------------------------------------------------------
// prep: style = w @ (rc*mod_w) + mod_b + 1; wt = rc_conv*conv_w*style;
// d = rsqrt(sum wt^2 + 1e-8); write bf16 weights swizzled as A-fragments:
// Wswz[b][tap][kstep][mfrag][lane][j]  (16B per lane per fragment)
//   co = mfrag*16 + (lane&15),  ci = kstep*32 + (lane>>4)*8 + j
// ---------------------------------------------------------------------------
__global__ void prep_kernel(const float* __restrict__ wv,
                            const float* __restrict__ conv_w,
                            const float* __restrict__ mod_w,
                            const float* __restrict__ mod_b,
                            unsigned short* __restrict__ Wswz) {
    const int b    = blockIdx.x;
    const int tid  = threadIdx.x;
    const int lane6 = tid & 63;
    const int part  = tid >> 6;
    __shared__ float red[256];
    __shared__ float style[64];
    __shared__ float dsc[64];
    const float rc_dense = 0.04419417382415922f;   // 1/sqrt(512)
    const float rc_conv  = 0.041666666666666664f;  // 1/sqrt(9*64)

    // style[ci]: 4 partial sums of 128 each
    float s = 0.f;
    const float* wb = wv + b * WDIM;
    for (int k = part * 128; k < part * 128 + 128; ++k)
        s += wb[k] * mod_w[k * 64 + lane6];
    red[tid] = s;
    __syncthreads();
    if (part == 0) {
        float tot = red[lane6] + red[64 + lane6] + red[128 + lane6] + red[192 + lane6];
        style[lane6] = tot * rc_dense + mod_b[lane6] + 1.0f;
    }
    __syncthreads();

    // sum of squares over (tap, ci) per co = lane6
    float qq = 0.f;
    for (int idx = part * 144; idx < part * 144 + 144; ++idx) {
        float v = conv_w[idx * 64 + lane6] * style[idx & 63];  // idx = tap*64+ci
        qq += v * v;
    }
    red[tid] = qq;
    __syncthreads();
    if (part == 0) {
        float tot = red[lane6] + red[64 + lane6] + red[128 + lane6] + red[192 + lane6];
        dsc[lane6] = rsqrtf(rc_conv * rc_conv * tot + 1e-8f);
    }
    __syncthreads();

    // swizzled bf16 write: 9 taps * 2 ksteps * 4 mfrags * 64 lanes = 4608 chunks
    for (int it = 0; it < 18; ++it) {
        int id  = it * 256 + tid;      // 0..4607
        int l   = id & 63;
        int mf  = (id >> 6) & 3;
        int ks  = (id >> 8) & 1;
        int t   = id >> 9;             // 0..8
        int co  = mf * 16 + (l & 15);
        int ci0 = ks * 32 + (l >> 4) * 8;
        float fco = rc_conv * dsc[co];
        ushortx8 ov;
#pragma unroll
        for (int j = 0; j < 8; ++j) {
            int ci = ci0 + j;
            float v = conv_w[(t * 64 + ci) * 64 + co] * style[ci] * fco;
            ov[j] = f2bf(v);
        }
        *reinterpret_cast<ushortx8*>(Wswz + (size_t)b * 36864 + id * 8) = ov;
    }
}

// ---------------------------------------------------------------------------
// conv: one block = one (b, 8x32 pixel tile), 256 threads = 4 waves.
// Wave wv owns pixel rows {2wv, 2wv+1} (n-frags 4wv..4wv+3).
// ---------------------------------------------------------------------------
__global__ __launch_bounds__(256, 3) void conv_kernel(
        const float* __restrict__ x,
        const unsigned short* __restrict__ Wswz,
        float* __restrict__ out) {
    __shared__ unsigned short xs[XR * XC * CPAD];  // 48960 B

    const int tid  = threadIdx.x;
    const int blk  = blockIdx.x;
    const int b    = blk >> 10;          // 1024 tiles per batch
    const int tile = blk & 1023;
    const int tr   = tile >> 4;          // 64 tile-rows
    const int tc   = tile & 15;          // 16 tile-cols
    const int h0   = tr * TILE_H;
    const int w0   = tc * TILE_W;
    const float* xb = x + (size_t)b * CIN * HH * WW;

    // ---- stage x tile (10 x 34 x 64ci) -> LDS bf16 [r][c][ci pad 72] ----
    // task = (ci_oct, r, c): 8*10*34 = 2720 tasks; 8 strided dword loads + 1 b128 write
    for (int it = 0; it < 11; ++it) {
        int id = it * 256 + tid;
        if (id < 2720) {
            int c   = id % 34;
            int rem = id / 34;
            int r   = rem % 10;
            int o8  = rem / 10;          // ci oct 0..7
            int rg  = h0 + r - 1;
            int cg  = w0 + c - 1;
            ushortx8 v;
            if (((unsigned)rg < (unsigned)HH) && ((unsigned)cg < (unsigned)WW)) {
                const float* p = xb + ((size_t)(o8 * 8) * HH + rg) * WW + cg;
#pragma unroll
                for (int j = 0; j < 8; ++j)
                    v[j] = f2bf(p[(size_t)j * HH * WW]);
            } else {
#pragma unroll
                for (int j = 0; j < 8; ++j) v[j] = 0;
            }
            *reinterpret_cast<ushortx8*>(&xs[(r * XC + c) * CPAD + o8 * 8]) = v;
        }
    }
    __syncthreads();

    // ---- implicit GEMM main loop ----
    const int l   = tid & 63;
    const int wv  = tid >> 6;
    const int m16 = l & 15;
    const int q   = l >> 4;

    f32x4 acc[4][4];
#pragma unroll
    for (int mf = 0; mf < 4; ++mf)
#pragma unroll
        for (int nf = 0; nf < 4; ++nf)
            acc[mf][nf] = (f32x4){0.f, 0.f, 0.f, 0.f};

    int Xbase[4];
#pragma unroll
    for (int nf = 0; nf < 4; ++nf) {
        int np = (wv * 4 + nf) * 16 + m16;   // pixel index in tile
        int pr = np >> 5, pc = np & 31;
        Xbase[nf] = (pr * XC + pc) * CPAD + q * 8;
    }
    const unsigned short* Wb = Wswz + (size_t)b * 36864 + l * 8;

    for (int kh = 0; kh < 3; ++kh) {
        for (int kw = 0; kw < 3; ++kw) {
            int t = kh * 3 + kw;
#pragma unroll
            for (int s = 0; s < 2; ++s) {
                const unsigned short* Wt = Wb + (t * 2 + s) * 2048;
                bf16x8 a[4], bb[4];
#pragma unroll
                for (int mf = 0; mf < 4; ++mf)
                    a[mf] = *reinterpret_cast<const bf16x8*>(Wt + mf * 512);
                int so = (kh * XC + kw) * CPAD + s * 32;
#pragma unroll
                for (int nf = 0; nf < 4; ++nf)
                    bb[nf] = *reinterpret_cast<const bf16x8*>(&xs[Xbase[nf] + so]);
#pragma unroll
                for (int mf = 0; mf < 4; ++mf)
#pragma unroll
                    for (int nf = 0; nf < 4; ++nf)
                        acc[mf][nf] = __builtin_amdgcn_mfma_f32_16x16x32_bf16(
                            a[mf], bb[nf], acc[mf][nf], 0, 0, 0);
            }
        }
    }

    // ---- epilogue: C/D layout col=lane&15 (pixel), row=q*4+reg (co) ----
    float* ob = out + (size_t)b * COUT * HH * WW;
#pragma unroll
    for (int nf = 0; nf < 4; ++nf) {
        int np = (wv * 4 + nf) * 16 + m16;
        int pr = np >> 5, pc = np & 31;
        int h = h0 + pr, wc = w0 + pc;
#pragma unroll
        for (int mf = 0; mf < 4; ++mf) {
            int co = mf * 16 + q * 4;
            float* po = ob + ((size_t)co * HH + h) * WW + wc;
#pragma unroll
            for (int reg = 0; reg < 4; ++reg)
                po[(size_t)reg * HH * WW] = acc[mf][nf][reg];
        }
    }
}

extern "C" void kernel_launch(void* const* d_in, const int* in_sizes, int n_in,
                              void* d_out, int out_size, void* d_ws, size_t ws_size,
                              hipStream_t stream) {
    const float* x      = (const float*)d_in[0];
    const float* w      = (const float*)d_in[1];
    const float* conv_w = (const float*)d_in[2];
    const float* mod_w  = (const float*)d_in[3];
    const float* mod_b  = (const float*)d_in[4];
    float* out = (float*)d_out;
    unsigned short* Wswz = (unsigned short*)d_ws;  // 4*36864 ushorts = 288 KB

    prep_kernel<<<4, 256, 0, stream>>>(w, conv_w, mod_w, mod_b, Wswz);
    conv_kernel<<<4096, 256, 0, stream>>>(x, Wswz, out);
}